// Round 1
// baseline (296.473 us; speedup 1.0000x reference)
//
#include <hip/hip_runtime.h>

#define BB 2048
#define EMB 128
#define NF 200
#define W_OUT 126
#define EPS 1e-5f

// ws layout (floats):
// [0,200)    sum1      [200,400)  ssq1
// [400,1000) sum2[k][f]  [1000,1600) ssq2[k][f]
// [1600,1800) scale1   [1800,2000) shift1
// [2000,2600) scale2[k][f]  [2600,3200) shift2[k][f]

__device__ __forceinline__ void load_rows(const int* __restrict__ xb, int b,
                                          const float* __restrict__ er,
                                          const float* __restrict__ ev,
                                          const float* volatile* rows_s,
                                          float (*hs)[EMB], int tid) {
  if (tid < 9) {
    const int* xr = xb + b * 10;
    const float* p;
    if (tid == 0)      p = ev + (size_t)xr[1] * EMB;   // fv0
    else if (tid == 1) p = er + (size_t)xr[0] * EMB;   // fr0
    else if (tid == 2) p = ev + (size_t)xr[3] * EMB;   // fv1
    else {
      int k = (tid - 3) >> 1;
      p = ((tid - 3) & 1) ? ev + (size_t)xr[5 + 2 * k] * EMB   // kv_k
                          : er + (size_t)xr[4 + 2 * k] * EMB;  // kr_k
    }
    rows_s[tid] = p;
  }
  __syncthreads();
  for (int e = tid; e < 9 * EMB; e += 256) {
    const float* rp = (const float*)rows_s[e >> 7];
    hs[e >> 7][e & 127] = rp[e & 127];
  }
  __syncthreads();
}

__global__ __launch_bounds__(256) void stats_kernel(
    const int* __restrict__ xb, const float* __restrict__ er,
    const float* __restrict__ ev, const float* __restrict__ w1,
    const float* __restrict__ w2, float* __restrict__ ws) {
  __shared__ float hs[9][EMB];
  __shared__ const float* volatile rows_s[9];
  const int tid = threadIdx.x;
  const int f = tid;
  float w1r[9], w2r[15];
  if (f < NF) {
#pragma unroll
    for (int j = 0; j < 9; j++)  w1r[j] = w1[f * 9 + j];
#pragma unroll
    for (int j = 0; j < 15; j++) w2r[j] = w2[f * 15 + j];
  }
  float a0 = 0.f, a1 = 0.f;
  float s2[3] = {0.f, 0.f, 0.f}, q2[3] = {0.f, 0.f, 0.f};

  for (int b = blockIdx.x; b < BB; b += gridDim.x) {
    __syncthreads();  // protect hs from previous iteration
    load_rows(xb, b, er, ev, rows_s, hs, tid);
    if (f < NF) {
      for (int x = 0; x < W_OUT; x++) {
        float r1 = 0.f, cm = 0.f;
#pragma unroll
        for (int j = 0; j < 3; j++) {
          float h0 = hs[0][x + j], h1 = hs[1][x + j], h2 = hs[2][x + j];
          r1 += h0 * w1r[j] + h1 * w1r[3 + j] + h2 * w1r[6 + j];
          cm += h0 * w2r[j] + h1 * w2r[3 + j] + h2 * w2r[6 + j];
        }
        a0 += r1; a1 += r1 * r1;
#pragma unroll
        for (int k = 0; k < 3; k++) {
          float rk = cm;
#pragma unroll
          for (int j = 0; j < 3; j++)
            rk += hs[3 + 2 * k][x + j] * w2r[9 + j] +
                  hs[4 + 2 * k][x + j] * w2r[12 + j];
          s2[k] += rk; q2[k] += rk * rk;
        }
      }
    }
  }
  if (f < NF) {
    atomicAdd(&ws[f], a0);
    atomicAdd(&ws[200 + f], a1);
#pragma unroll
    for (int k = 0; k < 3; k++) {
      atomicAdd(&ws[400 + k * 200 + f], s2[k]);
      atomicAdd(&ws[1000 + k * 200 + f], q2[k]);
    }
  }
}

__global__ __launch_bounds__(256) void finalize_kernel(
    const float* __restrict__ g1, const float* __restrict__ be1,
    const float* __restrict__ g2, const float* __restrict__ be2,
    float* __restrict__ ws) {
  const int f = threadIdx.x;
  if (f >= NF) return;
  const float invN = 1.0f / (float)(BB * W_OUT);
  float m = ws[f] * invN;
  float v = ws[200 + f] * invN - m * m;
  float sc = g1[f] * rsqrtf(v + EPS);
  ws[1600 + f] = sc;
  ws[1800 + f] = be1[f] - m * sc;
#pragma unroll
  for (int k = 0; k < 3; k++) {
    float mk = ws[400 + k * 200 + f] * invN;
    float vk = ws[1000 + k * 200 + f] * invN - mk * mk;
    float sck = g2[f] * rsqrtf(vk + EPS);
    ws[2000 + k * 200 + f] = sck;
    ws[2600 + k * 200 + f] = be2[f] - mk * sck;
  }
}

__global__ __launch_bounds__(256) void main_kernel(
    const int* __restrict__ xb, const float* __restrict__ er,
    const float* __restrict__ ev, const float* __restrict__ w1,
    const float* __restrict__ w2, const float* __restrict__ fcw,
    const float* __restrict__ fcb, const float* __restrict__ ws,
    float* __restrict__ out) {
  __shared__ float hs[9][EMB];
  __shared__ const float* volatile rows_s[9];
  __shared__ float red[4];
  const int tid = threadIdx.x;
  const int b = blockIdx.x;
  const int f = tid;

  float w1r[9], w2r[15];
  float sc1 = 0.f, sh1 = 0.f, sc2[3], sh2[3];
  const float* fp = fcw;
  if (f < NF) {
#pragma unroll
    for (int j = 0; j < 9; j++)  w1r[j] = w1[f * 9 + j];
#pragma unroll
    for (int j = 0; j < 15; j++) w2r[j] = w2[f * 15 + j];
    sc1 = ws[1600 + f]; sh1 = ws[1800 + f];
#pragma unroll
    for (int k = 0; k < 3; k++) {
      sc2[k] = ws[2000 + k * 200 + f];
      sh2[k] = ws[2600 + k * 200 + f];
    }
    fp = fcw + f * W_OUT;
  }

  load_rows(xb, b, er, ev, rows_s, hs, tid);

  float acc = 0.f;
  if (f < NF) {
    for (int x = 0; x < W_OUT; x++) {
      float r1 = 0.f, cm = 0.f;
#pragma unroll
      for (int j = 0; j < 3; j++) {
        float h0 = hs[0][x + j], h1 = hs[1][x + j], h2 = hs[2][x + j];
        r1 += h0 * w1r[j] + h1 * w1r[3 + j] + h2 * w1r[6 + j];
        cm += h0 * w2r[j] + h1 * w2r[3 + j] + h2 * w2r[6 + j];
      }
      float mv = r1 * sc1 + sh1;  // bn1 value (bias cancels in BN)
#pragma unroll
      for (int k = 0; k < 3; k++) {
        float rk = cm;
#pragma unroll
        for (int j = 0; j < 3; j++)
          rk += hs[3 + 2 * k][x + j] * w2r[9 + j] +
                hs[4 + 2 * k][x + j] * w2r[12 + j];
        mv = fminf(mv, rk * sc2[k] + sh2[k]);
      }
      // min of relus == relu of min
      acc += fmaxf(mv, 0.f) * fp[x];
    }
  }

  // block reduction: wave shuffle then LDS
#pragma unroll
  for (int off = 32; off > 0; off >>= 1)
    acc += __shfl_down(acc, off, 64);
  if ((tid & 63) == 0) red[tid >> 6] = acc;
  __syncthreads();
  if (tid == 0) out[b] = red[0] + red[1] + red[2] + red[3] + fcb[0];
}

extern "C" void kernel_launch(void* const* d_in, const int* in_sizes, int n_in,
                              void* d_out, int out_size, void* d_ws, size_t ws_size,
                              hipStream_t stream) {
  const int* xb    = (const int*)d_in[0];
  const float* er  = (const float*)d_in[3];
  const float* ev  = (const float*)d_in[4];
  const float* w1  = (const float*)d_in[5];
  const float* g1  = (const float*)d_in[7];
  const float* be1 = (const float*)d_in[8];
  const float* w2  = (const float*)d_in[9];
  const float* g2  = (const float*)d_in[11];
  const float* be2 = (const float*)d_in[12];
  const float* fcw = (const float*)d_in[13];
  const float* fcb = (const float*)d_in[14];
  float* ws  = (float*)d_ws;
  float* out = (float*)d_out;

  hipMemsetAsync(ws, 0, 1600 * sizeof(float), stream);
  hipLaunchKernelGGL(stats_kernel, dim3(512), dim3(256), 0, stream,
                     xb, er, ev, w1, w2, ws);
  hipLaunchKernelGGL(finalize_kernel, dim3(1), dim3(256), 0, stream,
                     g1, be1, g2, be2, ws);
  hipLaunchKernelGGL(main_kernel, dim3(BB), dim3(256), 0, stream,
                     xb, er, ev, w1, w2, fcw, fcb, ws, out);
}

// Round 2
// 244.509 us; speedup vs baseline: 1.2125x; 1.2125x over previous
//
#include <hip/hip_runtime.h>

#define BB 2048
#define EMB 128
#define NF 200
#define W_OUT 126
#define EPS 1e-5f

// ws layout (floats):
// [0,200)    sum1      [200,400)  ssq1
// [400,1000) sum2[k][f]  [1000,1600) ssq2[k][f]
// [1600,1800) scale1   [1800,2000) shift1
// [2000,2600) scale2[k][f]  [2600,3200) shift2[k][f]

__device__ __forceinline__ void load_rows(const int* __restrict__ xb, int b,
                                          const float* __restrict__ er,
                                          const float* __restrict__ ev,
                                          const float* volatile* rows_s,
                                          float (*hs)[EMB], int tid) {
  if (tid < 9) {
    const int* xr = xb + b * 10;
    const float* p;
    if (tid == 0)      p = ev + (size_t)xr[1] * EMB;   // fv0
    else if (tid == 1) p = er + (size_t)xr[0] * EMB;   // fr0
    else if (tid == 2) p = ev + (size_t)xr[3] * EMB;   // fv1
    else {
      int k = (tid - 3) >> 1;
      p = ((tid - 3) & 1) ? ev + (size_t)xr[5 + 2 * k] * EMB   // kv_k
                          : er + (size_t)xr[4 + 2 * k] * EMB;  // kr_k
    }
    rows_s[tid] = p;
  }
  __syncthreads();
  for (int e = tid; e < 9 * EMB; e += 256) {
    const float* rp = (const float*)rows_s[e >> 7];
    hs[e >> 7][e & 127] = rp[e & 127];
  }
  __syncthreads();
}

// One conv evaluation at a single x position. V0/V1/V2 are accessor macros
// giving h[row][x+0/1/2]. Produces r1 (conv1) and rk0..rk2 (conv2, k=0..2),
// then runs the per-position statement(s) in __VA_ARGS__.
#define CONV_BODY(V0, V1, V2, ...)                                          \
  {                                                                         \
    float r1 = V0(0) * w1r[0] + V1(0) * w1r[1] + V2(0) * w1r[2]             \
             + V0(1) * w1r[3] + V1(1) * w1r[4] + V2(1) * w1r[5]             \
             + V0(2) * w1r[6] + V1(2) * w1r[7] + V2(2) * w1r[8];            \
    float cm = V0(0) * w2r[0] + V1(0) * w2r[1] + V2(0) * w2r[2]             \
             + V0(1) * w2r[3] + V1(1) * w2r[4] + V2(1) * w2r[5]             \
             + V0(2) * w2r[6] + V1(2) * w2r[7] + V2(2) * w2r[8];            \
    float rk0 = cm + V0(3) * w2r[9]  + V1(3) * w2r[10] + V2(3) * w2r[11]    \
                   + V0(4) * w2r[12] + V1(4) * w2r[13] + V2(4) * w2r[14];   \
    float rk1 = cm + V0(5) * w2r[9]  + V1(5) * w2r[10] + V2(5) * w2r[11]    \
                   + V0(6) * w2r[12] + V1(6) * w2r[13] + V2(6) * w2r[14];   \
    float rk2 = cm + V0(7) * w2r[9]  + V1(7) * w2r[10] + V2(7) * w2r[11]    \
                   + V0(8) * w2r[12] + V1(8) * w2r[13] + V2(8) * w2r[14];   \
    __VA_ARGS__                                                             \
  }

// accessors: position A = x, position B = x+1
#define VA0(r) win[r].x
#define VA1(r) win[r].y
#define VA2(r) nxt[r].x
#define VB0(r) win[r].y
#define VB1(r) nxt[r].x
#define VB2(r) nxt[r].y

__global__ __launch_bounds__(256, 4) void stats_kernel(
    const int* __restrict__ xb, const float* __restrict__ er,
    const float* __restrict__ ev, const float* __restrict__ w1,
    const float* __restrict__ w2, float* __restrict__ ws) {
  __shared__ float hs[9][EMB];
  __shared__ const float* volatile rows_s[9];
  const int tid = threadIdx.x;
  const int f = tid;
  float w1r[9], w2r[15];
  if (f < NF) {
#pragma unroll
    for (int j = 0; j < 9; j++)  w1r[j] = w1[f * 9 + j];
#pragma unroll
    for (int j = 0; j < 15; j++) w2r[j] = w2[f * 15 + j];
  }
  float a0 = 0.f, a1 = 0.f;
  float s20 = 0.f, s21 = 0.f, s22 = 0.f;
  float q20 = 0.f, q21 = 0.f, q22 = 0.f;

  for (int b = blockIdx.x; b < BB; b += gridDim.x) {
    __syncthreads();  // protect hs from previous iteration
    load_rows(xb, b, er, ev, rows_s, hs, tid);
    if (f < NF) {
      float2 win[9], nxt[9];
#pragma unroll
      for (int r = 0; r < 9; r++) win[r] = *(const float2*)&hs[r][0];
#pragma unroll 1
      for (int c = 0; c < W_OUT / 2; c++) {
        const int x = 2 * c;
#pragma unroll
        for (int r = 0; r < 9; r++) nxt[r] = *(const float2*)&hs[r][x + 2];
        CONV_BODY(VA0, VA1, VA2,
          a0 += r1; a1 = fmaf(r1, r1, a1);
          s20 += rk0; q20 = fmaf(rk0, rk0, q20);
          s21 += rk1; q21 = fmaf(rk1, rk1, q21);
          s22 += rk2; q22 = fmaf(rk2, rk2, q22);)
        CONV_BODY(VB0, VB1, VB2,
          a0 += r1; a1 = fmaf(r1, r1, a1);
          s20 += rk0; q20 = fmaf(rk0, rk0, q20);
          s21 += rk1; q21 = fmaf(rk1, rk1, q21);
          s22 += rk2; q22 = fmaf(rk2, rk2, q22);)
#pragma unroll
        for (int r = 0; r < 9; r++) win[r] = nxt[r];
      }
    }
  }
  if (f < NF) {
    atomicAdd(&ws[f], a0);
    atomicAdd(&ws[200 + f], a1);
    atomicAdd(&ws[400 + f], s20);
    atomicAdd(&ws[600 + f], s21);
    atomicAdd(&ws[800 + f], s22);
    atomicAdd(&ws[1000 + f], q20);
    atomicAdd(&ws[1200 + f], q21);
    atomicAdd(&ws[1400 + f], q22);
  }
}

__global__ __launch_bounds__(256) void finalize_kernel(
    const float* __restrict__ g1, const float* __restrict__ be1,
    const float* __restrict__ g2, const float* __restrict__ be2,
    float* __restrict__ ws) {
  const int f = threadIdx.x;
  if (f >= NF) return;
  const float invN = 1.0f / (float)(BB * W_OUT);
  float m = ws[f] * invN;
  float v = ws[200 + f] * invN - m * m;
  float sc = g1[f] * rsqrtf(v + EPS);
  ws[1600 + f] = sc;
  ws[1800 + f] = be1[f] - m * sc;
#pragma unroll
  for (int k = 0; k < 3; k++) {
    float mk = ws[400 + k * 200 + f] * invN;
    float vk = ws[1000 + k * 200 + f] * invN - mk * mk;
    float sck = g2[f] * rsqrtf(vk + EPS);
    ws[2000 + k * 200 + f] = sck;
    ws[2600 + k * 200 + f] = be2[f] - mk * sck;
  }
}

__global__ __launch_bounds__(256, 4) void main_kernel(
    const int* __restrict__ xb, const float* __restrict__ er,
    const float* __restrict__ ev, const float* __restrict__ w1,
    const float* __restrict__ w2, const float* __restrict__ fcw,
    const float* __restrict__ fcb, const float* __restrict__ ws,
    float* __restrict__ out) {
  __shared__ float hs[9][EMB];
  __shared__ const float* volatile rows_s[9];
  __shared__ float red[4];
  const int tid = threadIdx.x;
  const int b = blockIdx.x;
  const int f = tid;

  float w1r[9], w2r[15];
  float sc1 = 0.f, sh1 = 0.f, sc2[3], sh2[3];
  const float* fp = fcw;
  if (f < NF) {
#pragma unroll
    for (int j = 0; j < 9; j++)  w1r[j] = w1[f * 9 + j];
#pragma unroll
    for (int j = 0; j < 15; j++) w2r[j] = w2[f * 15 + j];
    sc1 = ws[1600 + f]; sh1 = ws[1800 + f];
#pragma unroll
    for (int k = 0; k < 3; k++) {
      sc2[k] = ws[2000 + k * 200 + f];
      sh2[k] = ws[2600 + k * 200 + f];
    }
    fp = fcw + f * W_OUT;
  }

  load_rows(xb, b, er, ev, rows_s, hs, tid);

  float acc = 0.f;
  if (f < NF) {
    float2 win[9], nxt[9];
#pragma unroll
    for (int r = 0; r < 9; r++) win[r] = *(const float2*)&hs[r][0];
#pragma unroll 1
    for (int c = 0; c < W_OUT / 2; c++) {
      const int x = 2 * c;
#pragma unroll
      for (int r = 0; r < 9; r++) nxt[r] = *(const float2*)&hs[r][x + 2];
      float fpv0 = fp[x], fpv1 = fp[x + 1];
      CONV_BODY(VA0, VA1, VA2,
        float mv = fmaf(r1, sc1, sh1);
        mv = fminf(mv, fmaf(rk0, sc2[0], sh2[0]));
        mv = fminf(mv, fmaf(rk1, sc2[1], sh2[1]));
        mv = fminf(mv, fmaf(rk2, sc2[2], sh2[2]));
        acc = fmaf(fmaxf(mv, 0.f), fpv0, acc);)
      CONV_BODY(VB0, VB1, VB2,
        float mv = fmaf(r1, sc1, sh1);
        mv = fminf(mv, fmaf(rk0, sc2[0], sh2[0]));
        mv = fminf(mv, fmaf(rk1, sc2[1], sh2[1]));
        mv = fminf(mv, fmaf(rk2, sc2[2], sh2[2]));
        acc = fmaf(fmaxf(mv, 0.f), fpv1, acc);)
#pragma unroll
      for (int r = 0; r < 9; r++) win[r] = nxt[r];
    }
  }

  // block reduction: wave shuffle then LDS
#pragma unroll
  for (int off = 32; off > 0; off >>= 1)
    acc += __shfl_down(acc, off, 64);
  if ((tid & 63) == 0) red[tid >> 6] = acc;
  __syncthreads();
  if (tid == 0) out[b] = red[0] + red[1] + red[2] + red[3] + fcb[0];
}

extern "C" void kernel_launch(void* const* d_in, const int* in_sizes, int n_in,
                              void* d_out, int out_size, void* d_ws, size_t ws_size,
                              hipStream_t stream) {
  const int* xb    = (const int*)d_in[0];
  const float* er  = (const float*)d_in[3];
  const float* ev  = (const float*)d_in[4];
  const float* w1  = (const float*)d_in[5];
  const float* g1  = (const float*)d_in[7];
  const float* be1 = (const float*)d_in[8];
  const float* w2  = (const float*)d_in[9];
  const float* g2  = (const float*)d_in[11];
  const float* be2 = (const float*)d_in[12];
  const float* fcw = (const float*)d_in[13];
  const float* fcb = (const float*)d_in[14];
  float* ws  = (float*)d_ws;
  float* out = (float*)d_out;

  hipMemsetAsync(ws, 0, 1600 * sizeof(float), stream);
  hipLaunchKernelGGL(stats_kernel, dim3(512), dim3(256), 0, stream,
                     xb, er, ev, w1, w2, ws);
  hipLaunchKernelGGL(finalize_kernel, dim3(1), dim3(256), 0, stream,
                     g1, be1, g2, be2, ws);
  hipLaunchKernelGGL(main_kernel, dim3(BB), dim3(256), 0, stream,
                     xb, er, ev, w1, w2, fcw, fcb, ws, out);
}

// Round 3
// 156.910 us; speedup vs baseline: 1.8895x; 1.5583x over previous
//
#include <hip/hip_runtime.h>

#define BB 2048
#define EMB 128
#define NF 200
#define W_OUT 126
#define EPS 1e-5f

#define SLOTS 6
#define NTASK 42
#define NPAIR 33
#define NGRAM 297   // 33 pairs * 9 (j,j')
#define NSTAT 324   // + 27 window sums
#define STATS_BLOCKS 342  // 342*6 = 2052 >= 2048
#define FCWT_OFF 4096     // float offset of fcwT in ws

// ws layout (floats):
// [0,297)   Gram sums   [297,324) Sm[r][j]
// [1600,1800) scale1   [1800,2000) shift1
// [2000,2600) scale2[k][f]  [2600,3200) shift2[k][f]
// [4096, 4096+25200) fcwT[x][f] (if ws_size permits)

// 42 tasks: 33 Gram row-pairs + 9 (row, ones-row) pairs for window sums.
__device__ __constant__ unsigned char PA_t[NTASK] = {
  0,0,0,1,1,2,
  0,1,2,0,1,2, 3,3,4,
  0,1,2,0,1,2, 5,5,6,
  0,1,2,0,1,2, 7,7,8,
  0,1,2,3,4,5,6,7,8};
__device__ __constant__ unsigned char PB_t[NTASK] = {
  0,1,2,1,2,2,
  3,3,3,4,4,4, 3,4,4,
  5,5,5,6,6,6, 5,6,6,
  7,7,7,8,8,8, 7,8,8,
  9,9,9,9,9,9,9,9,9};

__global__ __launch_bounds__(256, 4) void stats_kernel(
    const int* __restrict__ xb, const float* __restrict__ er,
    const float* __restrict__ ev, float* __restrict__ ws) {
  __shared__ float hs[SLOTS][10][132];   // 132 stride: spread banks
  __shared__ const float* volatile rowp[SLOTS][9];
  __shared__ float red[NSTAT];
  const int tid = threadIdx.x;
  // ones rows + reduction buffer init (synced by barriers below)
  for (int e = tid; e < SLOTS * EMB; e += 256) hs[e / EMB][9][e & 127] = 1.0f;
  for (int e = tid; e < NSTAT; e += 256) red[e] = 0.f;

  const int base = blockIdx.x * SLOTS;
  if (tid < SLOTS * 9) {
    int s = tid / 9, r = tid % 9;
    int b = base + s;
    const float* p = nullptr;
    if (b < BB) {
      const int* xr = xb + b * 10;
      if (r == 0)      p = ev + (size_t)xr[1] * EMB;
      else if (r == 1) p = er + (size_t)xr[0] * EMB;
      else if (r == 2) p = ev + (size_t)xr[3] * EMB;
      else {
        int k = (r - 3) >> 1;
        p = ((r - 3) & 1) ? ev + (size_t)xr[5 + 2 * k] * EMB
                          : er + (size_t)xr[4 + 2 * k] * EMB;
      }
    }
    rowp[s][r] = p;
  }
  __syncthreads();
  for (int e = tid; e < SLOTS * 9 * EMB; e += 256) {
    int s = e / (9 * EMB), rem = e % (9 * EMB);
    int r = rem >> 7, col = rem & 127;
    const float* p = (const float*)rowp[s][r];
    hs[s][r][col] = p ? p[col] : 0.f;   // invalid samples contribute zeros
  }
  __syncthreads();

  const int slot = tid / NTASK;
  const int task = tid % NTASK;
  if (tid < SLOTS * NTASK) {
    const float* A  = &hs[slot][PA_t[task]][0];
    const float* Bq = &hs[slot][PB_t[task]][0];
    float a00 = 0.f, a01 = 0.f, a02 = 0.f;
    float a10 = 0.f, a11 = 0.f, a12 = 0.f;
    float a20 = 0.f, a21 = 0.f, a22 = 0.f;
    float wa0 = A[0], wa1 = A[1], wb0 = Bq[0], wb1 = Bq[1];
#pragma unroll 3
    for (int x = 0; x < W_OUT; ++x) {
      float wa2 = A[x + 2], wb2 = Bq[x + 2];
      a00 = fmaf(wa0, wb0, a00); a01 = fmaf(wa0, wb1, a01); a02 = fmaf(wa0, wb2, a02);
      a10 = fmaf(wa1, wb0, a10); a11 = fmaf(wa1, wb1, a11); a12 = fmaf(wa1, wb2, a12);
      a20 = fmaf(wa2, wb0, a20); a21 = fmaf(wa2, wb1, a21); a22 = fmaf(wa2, wb2, a22);
      wa0 = wa1; wa1 = wa2; wb0 = wb1; wb1 = wb2;
    }
    if (task < NPAIR) {
      const int o = task * 9;
      atomicAdd(&red[o + 0], a00); atomicAdd(&red[o + 1], a01); atomicAdd(&red[o + 2], a02);
      atomicAdd(&red[o + 3], a10); atomicAdd(&red[o + 4], a11); atomicAdd(&red[o + 5], a12);
      atomicAdd(&red[o + 6], a20); atomicAdd(&red[o + 7], a21); atomicAdd(&red[o + 8], a22);
    } else {
      const int o = NGRAM + (task - NPAIR) * 3;  // ones-row: col j'=0 holds Sm[r][j]
      atomicAdd(&red[o + 0], a00); atomicAdd(&red[o + 1], a10); atomicAdd(&red[o + 2], a20);
    }
  }
  __syncthreads();
  for (int e = tid; e < NSTAT; e += 256) atomicAdd(&ws[e], red[e]);
}

__device__ __forceinline__ float qform(const float* G, int p,
                                       const float* wa, const float* wb) {
  float t = 0.f;
#pragma unroll
  for (int j = 0; j < 3; j++)
#pragma unroll
    for (int jp = 0; jp < 3; jp++)
      t = fmaf(wa[j] * wb[jp], G[p * 9 + j * 3 + jp], t);
  return t;
}

__global__ __launch_bounds__(256) void finalize_kernel(
    const float* __restrict__ w1, const float* __restrict__ w2,
    const float* __restrict__ g1, const float* __restrict__ be1,
    const float* __restrict__ g2, const float* __restrict__ be2,
    float* __restrict__ ws) {
  __shared__ float G[NSTAT];
  const int tid = threadIdx.x;
  for (int e = tid; e < NSTAT; e += 256) G[e] = ws[e];
  __syncthreads();
  const int f = tid;
  if (f >= NF) return;
  float w1r[9], w2r[15];
#pragma unroll
  for (int j = 0; j < 9; j++)  w1r[j] = w1[f * 9 + j];
#pragma unroll
  for (int j = 0; j < 15; j++) w2r[j] = w2[f * 15 + j];
  const float invN = 1.0f / (float)(BB * W_OUT);
  const float* Sm = &G[NGRAM];

  // conv1
  float m1 = 0.f;
#pragma unroll
  for (int r = 0; r < 3; r++)
#pragma unroll
    for (int j = 0; j < 3; j++) m1 = fmaf(w1r[r * 3 + j], Sm[r * 3 + j], m1);
  float q1 = qform(G, 0, w1r, w1r) + 2.f * qform(G, 1, w1r, w1r + 3)
           + 2.f * qform(G, 2, w1r, w1r + 6) + qform(G, 3, w1r + 3, w1r + 3)
           + 2.f * qform(G, 4, w1r + 3, w1r + 6) + qform(G, 5, w1r + 6, w1r + 6);
  m1 *= invN;
  float v1 = q1 * invN - m1 * m1;
  float sc1 = g1[f] * rsqrtf(v1 + EPS);
  ws[1600 + f] = sc1;
  ws[1800 + f] = be1[f] - m1 * sc1;

  // conv2 common part of mean
  float mc = 0.f;
#pragma unroll
  for (int r = 0; r < 3; r++)
#pragma unroll
    for (int j = 0; j < 3; j++) mc = fmaf(w2r[r * 3 + j], Sm[r * 3 + j], mc);
  float qc = qform(G, 0, w2r, w2r) + 2.f * qform(G, 1, w2r, w2r + 3)
           + 2.f * qform(G, 2, w2r, w2r + 6) + qform(G, 3, w2r + 3, w2r + 3)
           + 2.f * qform(G, 4, w2r + 3, w2r + 6) + qform(G, 5, w2r + 6, w2r + 6);
  const float* wA = w2r + 9;
  const float* wB = w2r + 12;
#pragma unroll
  for (int k = 0; k < 3; k++) {
    const int a = 3 + 2 * k, b = 4 + 2 * k, p0 = 6 + 9 * k;
    float m2 = mc;
#pragma unroll
    for (int j = 0; j < 3; j++) {
      m2 = fmaf(wA[j], Sm[a * 3 + j], m2);
      m2 = fmaf(wB[j], Sm[b * 3 + j], m2);
    }
    float q2 = qc
      + 2.f * (qform(G, p0 + 0, w2r, wA) + qform(G, p0 + 1, w2r + 3, wA)
             + qform(G, p0 + 2, w2r + 6, wA) + qform(G, p0 + 3, w2r, wB)
             + qform(G, p0 + 4, w2r + 3, wB) + qform(G, p0 + 5, w2r + 6, wB))
      + qform(G, p0 + 6, wA, wA) + 2.f * qform(G, p0 + 7, wA, wB)
      + qform(G, p0 + 8, wB, wB);
    m2 *= invN;
    float v2 = q2 * invN - m2 * m2;
    float sck = g2[f] * rsqrtf(v2 + EPS);
    ws[2000 + k * 200 + f] = sck;
    ws[2600 + k * 200 + f] = be2[f] - m2 * sck;
  }
}

__global__ void transpose_fcw(const float* __restrict__ fcw,
                              float* __restrict__ fcwT) {
  int i = blockIdx.x * 256 + threadIdx.x;
  if (i < W_OUT * NF) {
    int x = i / NF, f = i % NF;
    fcwT[i] = fcw[f * W_OUT + x];
  }
}

__device__ __forceinline__ void load_rows(const int* __restrict__ xb, int b,
                                          const float* __restrict__ er,
                                          const float* __restrict__ ev,
                                          const float* volatile* rows_s,
                                          float (*hs)[EMB], int tid) {
  if (tid < 9) {
    const int* xr = xb + b * 10;
    const float* p;
    if (tid == 0)      p = ev + (size_t)xr[1] * EMB;
    else if (tid == 1) p = er + (size_t)xr[0] * EMB;
    else if (tid == 2) p = ev + (size_t)xr[3] * EMB;
    else {
      int k = (tid - 3) >> 1;
      p = ((tid - 3) & 1) ? ev + (size_t)xr[5 + 2 * k] * EMB
                          : er + (size_t)xr[4 + 2 * k] * EMB;
    }
    rows_s[tid] = p;
  }
  __syncthreads();
  for (int e = tid; e < 9 * EMB; e += 256) {
    const float* rp = (const float*)rows_s[e >> 7];
    hs[e >> 7][e & 127] = rp[e & 127];
  }
  __syncthreads();
}

#define CONV_BODY(V0, V1, V2, ...)                                          \
  {                                                                         \
    float r1 = V0(0) * w1r[0] + V1(0) * w1r[1] + V2(0) * w1r[2]             \
             + V0(1) * w1r[3] + V1(1) * w1r[4] + V2(1) * w1r[5]             \
             + V0(2) * w1r[6] + V1(2) * w1r[7] + V2(2) * w1r[8];            \
    float cm = V0(0) * w2r[0] + V1(0) * w2r[1] + V2(0) * w2r[2]             \
             + V0(1) * w2r[3] + V1(1) * w2r[4] + V2(1) * w2r[5]             \
             + V0(2) * w2r[6] + V1(2) * w2r[7] + V2(2) * w2r[8];            \
    float rk0 = cm + V0(3) * w2r[9]  + V1(3) * w2r[10] + V2(3) * w2r[11]    \
                   + V0(4) * w2r[12] + V1(4) * w2r[13] + V2(4) * w2r[14];   \
    float rk1 = cm + V0(5) * w2r[9]  + V1(5) * w2r[10] + V2(5) * w2r[11]    \
                   + V0(6) * w2r[12] + V1(6) * w2r[13] + V2(6) * w2r[14];   \
    float rk2 = cm + V0(7) * w2r[9]  + V1(7) * w2r[10] + V2(7) * w2r[11]    \
                   + V0(8) * w2r[12] + V1(8) * w2r[13] + V2(8) * w2r[14];   \
    __VA_ARGS__                                                             \
  }

#define VA0(r) win[r].x
#define VA1(r) win[r].y
#define VA2(r) nxt[r].x
#define VB0(r) win[r].y
#define VB1(r) nxt[r].x
#define VB2(r) nxt[r].y

__global__ __launch_bounds__(256, 4) void main_kernel(
    const int* __restrict__ xb, const float* __restrict__ er,
    const float* __restrict__ ev, const float* __restrict__ w1,
    const float* __restrict__ w2, const float* __restrict__ fcw,
    const float* __restrict__ fcwT, const float* __restrict__ fcb,
    const float* __restrict__ ws, float* __restrict__ out) {
  __shared__ float hs[9][EMB];
  __shared__ const float* volatile rows_s[9];
  __shared__ float red[4];
  const int tid = threadIdx.x;
  const int b = blockIdx.x;
  const int f = tid;

  float w1r[9], w2r[15];
  float sc1 = 0.f, sh1 = 0.f, sc2[3], sh2[3];
  const float* fq = fcw;
  int fstep = 1;
  if (f < NF) {
#pragma unroll
    for (int j = 0; j < 9; j++)  w1r[j] = w1[f * 9 + j];
#pragma unroll
    for (int j = 0; j < 15; j++) w2r[j] = w2[f * 15 + j];
    sc1 = ws[1600 + f]; sh1 = ws[1800 + f];
#pragma unroll
    for (int k = 0; k < 3; k++) {
      sc2[k] = ws[2000 + k * 200 + f];
      sh2[k] = ws[2600 + k * 200 + f];
    }
    if (fcwT) { fq = fcwT + f; fstep = NF; }   // coalesced: lanes read x*NF+f
    else      { fq = fcw + f * W_OUT; }
  }

  load_rows(xb, b, er, ev, rows_s, hs, tid);

  float acc = 0.f;
  if (f < NF) {
    float2 win[9], nxt[9];
#pragma unroll
    for (int r = 0; r < 9; r++) win[r] = *(const float2*)&hs[r][0];
#pragma unroll 3
    for (int c = 0; c < W_OUT / 2; c++) {
      const int x = 2 * c;
#pragma unroll
      for (int r = 0; r < 9; r++) nxt[r] = *(const float2*)&hs[r][x + 2];
      float fpv0 = fq[x * fstep], fpv1 = fq[(x + 1) * fstep];
      CONV_BODY(VA0, VA1, VA2,
        float mv = fmaf(r1, sc1, sh1);
        mv = fminf(mv, fmaf(rk0, sc2[0], sh2[0]));
        mv = fminf(mv, fmaf(rk1, sc2[1], sh2[1]));
        mv = fminf(mv, fmaf(rk2, sc2[2], sh2[2]));
        acc = fmaf(fmaxf(mv, 0.f), fpv0, acc);)
      CONV_BODY(VB0, VB1, VB2,
        float mv = fmaf(r1, sc1, sh1);
        mv = fminf(mv, fmaf(rk0, sc2[0], sh2[0]));
        mv = fminf(mv, fmaf(rk1, sc2[1], sh2[1]));
        mv = fminf(mv, fmaf(rk2, sc2[2], sh2[2]));
        acc = fmaf(fmaxf(mv, 0.f), fpv1, acc);)
#pragma unroll
      for (int r = 0; r < 9; r++) win[r] = nxt[r];
    }
  }

#pragma unroll
  for (int off = 32; off > 0; off >>= 1)
    acc += __shfl_down(acc, off, 64);
  if ((tid & 63) == 0) red[tid >> 6] = acc;
  __syncthreads();
  if (tid == 0) out[b] = red[0] + red[1] + red[2] + red[3] + fcb[0];
}

extern "C" void kernel_launch(void* const* d_in, const int* in_sizes, int n_in,
                              void* d_out, int out_size, void* d_ws, size_t ws_size,
                              hipStream_t stream) {
  const int* xb    = (const int*)d_in[0];
  const float* er  = (const float*)d_in[3];
  const float* ev  = (const float*)d_in[4];
  const float* w1  = (const float*)d_in[5];
  const float* g1  = (const float*)d_in[7];
  const float* be1 = (const float*)d_in[8];
  const float* w2  = (const float*)d_in[9];
  const float* g2  = (const float*)d_in[11];
  const float* be2 = (const float*)d_in[12];
  const float* fcw = (const float*)d_in[13];
  const float* fcb = (const float*)d_in[14];
  float* ws  = (float*)d_ws;
  float* out = (float*)d_out;

  const size_t need = (size_t)(FCWT_OFF + W_OUT * NF) * sizeof(float);
  float* fcwT = (ws_size >= need) ? ws + FCWT_OFF : nullptr;

  hipMemsetAsync(ws, 0, NSTAT * sizeof(float), stream);
  if (fcwT)
    hipLaunchKernelGGL(transpose_fcw, dim3((W_OUT * NF + 255) / 256), dim3(256),
                       0, stream, fcw, fcwT);
  hipLaunchKernelGGL(stats_kernel, dim3(STATS_BLOCKS), dim3(256), 0, stream,
                     xb, er, ev, ws);
  hipLaunchKernelGGL(finalize_kernel, dim3(1), dim3(256), 0, stream,
                     w1, w2, g1, be1, g2, be2, ws);
  hipLaunchKernelGGL(main_kernel, dim3(BB), dim3(256), 0, stream,
                     xb, er, ev, w1, w2, fcw, fcwT, fcb, ws, out);
}

// Round 4
// 97.635 us; speedup vs baseline: 3.0366x; 1.6071x over previous
//
#include <hip/hip_runtime.h>
#include <hip/hip_fp16.h>

#define BB 2048
#define EMB 128
#define NF 200
#define W_OUT 126
#define EPS 1e-5f

#define SPB 4                     // samples per block (2 pairs)
#define MAIN_BLOCKS (BB / SPB)    // 512

#define SLOTS 6
#define NTASK 42
#define NPAIR 33
#define NGRAM 297
#define NSTAT 324
#define STATS_BLOCKS 342

typedef float f32x2 __attribute__((ext_vector_type(2)));

__device__ __forceinline__ f32x2 fma2(f32x2 a, float s, f32x2 c) {
  return __builtin_elementwise_fma(a, (f32x2){s, s}, c);
}
__device__ __forceinline__ f32x2 fmss(f32x2 a, float s, float sh) {
  return __builtin_elementwise_fma(a, (f32x2){s, s}, (f32x2){sh, sh});
}
__device__ __forceinline__ f32x2 min2(f32x2 a, f32x2 b) {
  return __builtin_elementwise_min(a, b);
}

// ---------------- stats (Gram) + finalize: unchanged from R3 (proven) -------
__device__ __constant__ unsigned char PA_t[NTASK] = {
  0,0,0,1,1,2,
  0,1,2,0,1,2, 3,3,4,
  0,1,2,0,1,2, 5,5,6,
  0,1,2,0,1,2, 7,7,8,
  0,1,2,3,4,5,6,7,8};
__device__ __constant__ unsigned char PB_t[NTASK] = {
  0,1,2,1,2,2,
  3,3,3,4,4,4, 3,4,4,
  5,5,5,6,6,6, 5,6,6,
  7,7,7,8,8,8, 7,8,8,
  9,9,9,9,9,9,9,9,9};

__global__ __launch_bounds__(256, 4) void stats_kernel(
    const int* __restrict__ xb, const float* __restrict__ er,
    const float* __restrict__ ev, float* __restrict__ ws) {
  __shared__ float hs[SLOTS][10][132];
  __shared__ const float* volatile rowp[SLOTS][9];
  __shared__ float red[NSTAT];
  const int tid = threadIdx.x;
  for (int e = tid; e < SLOTS * EMB; e += 256) hs[e / EMB][9][e & 127] = 1.0f;
  for (int e = tid; e < NSTAT; e += 256) red[e] = 0.f;

  const int base = blockIdx.x * SLOTS;
  if (tid < SLOTS * 9) {
    int s = tid / 9, r = tid % 9;
    int b = base + s;
    const float* p = nullptr;
    if (b < BB) {
      const int* xr = xb + b * 10;
      if (r == 0)      p = ev + (size_t)xr[1] * EMB;
      else if (r == 1) p = er + (size_t)xr[0] * EMB;
      else if (r == 2) p = ev + (size_t)xr[3] * EMB;
      else {
        int k = (r - 3) >> 1;
        p = ((r - 3) & 1) ? ev + (size_t)xr[5 + 2 * k] * EMB
                          : er + (size_t)xr[4 + 2 * k] * EMB;
      }
    }
    rowp[s][r] = p;
  }
  __syncthreads();
  for (int e = tid; e < SLOTS * 9 * EMB; e += 256) {
    int s = e / (9 * EMB), rem = e % (9 * EMB);
    int r = rem >> 7, col = rem & 127;
    const float* p = (const float*)rowp[s][r];
    hs[s][r][col] = p ? p[col] : 0.f;
  }
  __syncthreads();

  const int slot = tid / NTASK;
  const int task = tid % NTASK;
  if (tid < SLOTS * NTASK) {
    const float* A  = &hs[slot][PA_t[task]][0];
    const float* Bq = &hs[slot][PB_t[task]][0];
    float a00 = 0.f, a01 = 0.f, a02 = 0.f;
    float a10 = 0.f, a11 = 0.f, a12 = 0.f;
    float a20 = 0.f, a21 = 0.f, a22 = 0.f;
    float wa0 = A[0], wa1 = A[1], wb0 = Bq[0], wb1 = Bq[1];
#pragma unroll 3
    for (int x = 0; x < W_OUT; ++x) {
      float wa2 = A[x + 2], wb2 = Bq[x + 2];
      a00 = fmaf(wa0, wb0, a00); a01 = fmaf(wa0, wb1, a01); a02 = fmaf(wa0, wb2, a02);
      a10 = fmaf(wa1, wb0, a10); a11 = fmaf(wa1, wb1, a11); a12 = fmaf(wa1, wb2, a12);
      a20 = fmaf(wa2, wb0, a20); a21 = fmaf(wa2, wb1, a21); a22 = fmaf(wa2, wb2, a22);
      wa0 = wa1; wa1 = wa2; wb0 = wb1; wb1 = wb2;
    }
    if (task < NPAIR) {
      const int o = task * 9;
      atomicAdd(&red[o + 0], a00); atomicAdd(&red[o + 1], a01); atomicAdd(&red[o + 2], a02);
      atomicAdd(&red[o + 3], a10); atomicAdd(&red[o + 4], a11); atomicAdd(&red[o + 5], a12);
      atomicAdd(&red[o + 6], a20); atomicAdd(&red[o + 7], a21); atomicAdd(&red[o + 8], a22);
    } else {
      const int o = NGRAM + (task - NPAIR) * 3;
      atomicAdd(&red[o + 0], a00); atomicAdd(&red[o + 1], a10); atomicAdd(&red[o + 2], a20);
    }
  }
  __syncthreads();
  for (int e = tid; e < NSTAT; e += 256) atomicAdd(&ws[e], red[e]);
}

__device__ __forceinline__ float qform(const float* G, int p,
                                       const float* wa, const float* wb) {
  float t = 0.f;
#pragma unroll
  for (int j = 0; j < 3; j++)
#pragma unroll
    for (int jp = 0; jp < 3; jp++)
      t = fmaf(wa[j] * wb[jp], G[p * 9 + j * 3 + jp], t);
  return t;
}

__global__ __launch_bounds__(256) void finalize_kernel(
    const float* __restrict__ w1, const float* __restrict__ w2,
    const float* __restrict__ g1, const float* __restrict__ be1,
    const float* __restrict__ g2, const float* __restrict__ be2,
    float* __restrict__ ws) {
  __shared__ float G[NSTAT];
  const int tid = threadIdx.x;
  for (int e = tid; e < NSTAT; e += 256) G[e] = ws[e];
  __syncthreads();
  const int f = tid;
  if (f >= NF) return;
  float w1r[9], w2r[15];
#pragma unroll
  for (int j = 0; j < 9; j++)  w1r[j] = w1[f * 9 + j];
#pragma unroll
  for (int j = 0; j < 15; j++) w2r[j] = w2[f * 15 + j];
  const float invN = 1.0f / (float)(BB * W_OUT);
  const float* Sm = &G[NGRAM];

  float m1 = 0.f;
#pragma unroll
  for (int r = 0; r < 3; r++)
#pragma unroll
    for (int j = 0; j < 3; j++) m1 = fmaf(w1r[r * 3 + j], Sm[r * 3 + j], m1);
  float q1 = qform(G, 0, w1r, w1r) + 2.f * qform(G, 1, w1r, w1r + 3)
           + 2.f * qform(G, 2, w1r, w1r + 6) + qform(G, 3, w1r + 3, w1r + 3)
           + 2.f * qform(G, 4, w1r + 3, w1r + 6) + qform(G, 5, w1r + 6, w1r + 6);
  m1 *= invN;
  float v1 = q1 * invN - m1 * m1;
  float sc1 = g1[f] * rsqrtf(v1 + EPS);
  ws[1600 + f] = sc1;
  ws[1800 + f] = be1[f] - m1 * sc1;

  float mc = 0.f;
#pragma unroll
  for (int r = 0; r < 3; r++)
#pragma unroll
    for (int j = 0; j < 3; j++) mc = fmaf(w2r[r * 3 + j], Sm[r * 3 + j], mc);
  float qc = qform(G, 0, w2r, w2r) + 2.f * qform(G, 1, w2r, w2r + 3)
           + 2.f * qform(G, 2, w2r, w2r + 6) + qform(G, 3, w2r + 3, w2r + 3)
           + 2.f * qform(G, 4, w2r + 3, w2r + 6) + qform(G, 5, w2r + 6, w2r + 6);
  const float* wA = w2r + 9;
  const float* wB = w2r + 12;
#pragma unroll
  for (int k = 0; k < 3; k++) {
    const int a = 3 + 2 * k, b = 4 + 2 * k, p0 = 6 + 9 * k;
    float m2 = mc;
#pragma unroll
    for (int j = 0; j < 3; j++) {
      m2 = fmaf(wA[j], Sm[a * 3 + j], m2);
      m2 = fmaf(wB[j], Sm[b * 3 + j], m2);
    }
    float q2 = qc
      + 2.f * (qform(G, p0 + 0, w2r, wA) + qform(G, p0 + 1, w2r + 3, wA)
             + qform(G, p0 + 2, w2r + 6, wA) + qform(G, p0 + 3, w2r, wB)
             + qform(G, p0 + 4, w2r + 3, wB) + qform(G, p0 + 5, w2r + 6, wB))
      + qform(G, p0 + 6, wA, wA) + 2.f * qform(G, p0 + 7, wA, wB)
      + qform(G, p0 + 8, wB, wB);
    m2 *= invN;
    float v2 = q2 * invN - m2 * m2;
    float sck = g2[f] * rsqrtf(v2 + EPS);
    ws[2000 + k * 200 + f] = sck;
    ws[2600 + k * 200 + f] = be2[f] - m2 * sck;
  }
}

// ---------------- main: sample-paired pk-f32, all inner-loop data in LDS ----

__device__ __forceinline__ void loadcol(f32x2 (&d)[9],
                                        const f32x2 (&hp)[9][EMB], int col) {
#pragma unroll
  for (int r = 0; r < 9; r++) d[r] = hp[r][col];
}

__device__ __forceinline__ f32x2 dopos(
    const f32x2 (&A)[9], const f32x2 (&B)[9], const f32x2 (&C)[9],
    const float (&w1r)[9], const float (&w2r)[15],
    float sc1, float sh1, const float (&sc2)[3], const float (&sh2)[3],
    float fpv, f32x2 acc) {
  f32x2 r1 = A[0] * w1r[0];
  r1 = fma2(B[0], w1r[1], r1); r1 = fma2(C[0], w1r[2], r1);
  r1 = fma2(A[1], w1r[3], r1); r1 = fma2(B[1], w1r[4], r1);
  r1 = fma2(C[1], w1r[5], r1); r1 = fma2(A[2], w1r[6], r1);
  r1 = fma2(B[2], w1r[7], r1); r1 = fma2(C[2], w1r[8], r1);
  f32x2 cm = A[0] * w2r[0];
  cm = fma2(B[0], w2r[1], cm); cm = fma2(C[0], w2r[2], cm);
  cm = fma2(A[1], w2r[3], cm); cm = fma2(B[1], w2r[4], cm);
  cm = fma2(C[1], w2r[5], cm); cm = fma2(A[2], w2r[6], cm);
  cm = fma2(B[2], w2r[7], cm); cm = fma2(C[2], w2r[8], cm);
  f32x2 rk0 = fma2(A[3], w2r[9], cm);
  rk0 = fma2(B[3], w2r[10], rk0); rk0 = fma2(C[3], w2r[11], rk0);
  rk0 = fma2(A[4], w2r[12], rk0); rk0 = fma2(B[4], w2r[13], rk0);
  rk0 = fma2(C[4], w2r[14], rk0);
  f32x2 rk1 = fma2(A[5], w2r[9], cm);
  rk1 = fma2(B[5], w2r[10], rk1); rk1 = fma2(C[5], w2r[11], rk1);
  rk1 = fma2(A[6], w2r[12], rk1); rk1 = fma2(B[6], w2r[13], rk1);
  rk1 = fma2(C[6], w2r[14], rk1);
  f32x2 rk2 = fma2(A[7], w2r[9], cm);
  rk2 = fma2(B[7], w2r[10], rk2); rk2 = fma2(C[7], w2r[11], rk2);
  rk2 = fma2(A[8], w2r[12], rk2); rk2 = fma2(B[8], w2r[13], rk2);
  rk2 = fma2(C[8], w2r[14], rk2);
  f32x2 mv = fmss(r1, sc1, sh1);
  mv = min2(mv, fmss(rk0, sc2[0], sh2[0]));
  mv = min2(mv, fmss(rk1, sc2[1], sh2[1]));
  mv = min2(mv, fmss(rk2, sc2[2], sh2[2]));
  mv = __builtin_elementwise_max(mv, (f32x2){0.f, 0.f});
  return fma2(mv, fpv, acc);
}

__global__ __launch_bounds__(256, 2) void main_kernel(
    const int* __restrict__ xb, const float* __restrict__ er,
    const float* __restrict__ ev, const float* __restrict__ w1,
    const float* __restrict__ w2, const float* __restrict__ fcw,
    const float* __restrict__ fcb, const float* __restrict__ ws,
    float* __restrict__ out) {
  __shared__ f32x2 hsI[2][9][EMB];     // 18.4 KB: paired samples
  __shared__ __half2 fcwP[63][201];    // 50.6 KB: fc weights, fp16 x-pairs
  __shared__ const float* rowp[SPB][9];
  __shared__ float red[2][4][2];       // [pair][wave][sample-in-pair]
  const int tid = threadIdx.x;
  const int f = tid;
  const int base = blockIdx.x * SPB;

  // Phase 1: bounce conv weights through LDS (coalesced global reads),
  // and resolve the embedding row pointers.
  float* wsc = (float*)&fcwP[0][0];    // scratch overlay (19.2 KB <= 50.6 KB)
  for (int i = tid; i < NF * 9; i += 256)  wsc[i] = w1[i];
  for (int i = tid; i < NF * 15; i += 256) wsc[NF * 9 + i] = w2[i];
  if (tid < SPB * 9) {
    int s = tid / 9, r = tid % 9;
    const int* xr = xb + (size_t)(base + s) * 10;
    const float* p;
    if (r == 0)      p = ev + (size_t)xr[1] * EMB;
    else if (r == 1) p = er + (size_t)xr[0] * EMB;
    else if (r == 2) p = ev + (size_t)xr[3] * EMB;
    else {
      int k = (r - 3) >> 1;
      p = ((r - 3) & 1) ? ev + (size_t)xr[5 + 2 * k] * EMB
                        : er + (size_t)xr[4 + 2 * k] * EMB;
    }
    rowp[s][r] = p;
  }
  __syncthreads();

  float w1r[9], w2r[15];
  float sc1 = 0.f, sh1 = 0.f, sc2[3] = {0.f, 0.f, 0.f}, sh2[3] = {0.f, 0.f, 0.f};
  if (f < NF) {
#pragma unroll
    for (int j = 0; j < 9; j++)  w1r[j] = wsc[f * 9 + j];
#pragma unroll
    for (int j = 0; j < 15; j++) w2r[j] = wsc[NF * 9 + f * 15 + j];
    sc1 = ws[1600 + f]; sh1 = ws[1800 + f];
#pragma unroll
    for (int k = 0; k < 3; k++) {
      sc2[k] = ws[2000 + k * 200 + f];
      sh2[k] = ws[2600 + k * 200 + f];
    }
  }
  __syncthreads();  // done with wsc scratch

  // Phase 2: stage fc weights (fp16 pairs) and paired embedding rows.
  for (int i = tid; i < 63 * NF; i += 256) {
    int ff = i / 63, c = i % 63;
    const float2 v = *(const float2*)(fcw + 2 * (size_t)i);  // fcw[ff][2c..2c+1]
    fcwP[c][ff] = __floats2half2_rn(v.x, v.y);
  }
  for (int e = tid; e < 2 * 9 * EMB; e += 256) {
    int p = e / (9 * EMB), rem = e % (9 * EMB);
    int r = rem >> 7, x = rem & 127;
    const float* ra = rowp[2 * p][r];
    const float* rb = rowp[2 * p + 1][r];
    hsI[p][r][x] = (f32x2){ra[x], rb[x]};
  }
  __syncthreads();

  // Phase 3: compute, one sample-pair at a time.
#pragma unroll 1
  for (int p = 0; p < 2; p++) {
    f32x2 acc = {0.f, 0.f};
    if (f < NF) {
      f32x2 h0[9], h1[9], h2[9];
      loadcol(h0, hsI[p], 0);
      loadcol(h1, hsI[p], 1);
#pragma unroll 1
      for (int it = 0; it < 21; it++) {
        const int x = it * 6;
        const __half2 fcA = fcwP[3 * it + 0][f];
        const __half2 fcB = fcwP[3 * it + 1][f];
        const __half2 fcC = fcwP[3 * it + 2][f];
        loadcol(h2, hsI[p], x + 2);
        acc = dopos(h0, h1, h2, w1r, w2r, sc1, sh1, sc2, sh2, __low2float(fcA), acc);
        loadcol(h0, hsI[p], x + 3);
        acc = dopos(h1, h2, h0, w1r, w2r, sc1, sh1, sc2, sh2, __high2float(fcA), acc);
        loadcol(h1, hsI[p], x + 4);
        acc = dopos(h2, h0, h1, w1r, w2r, sc1, sh1, sc2, sh2, __low2float(fcB), acc);
        loadcol(h2, hsI[p], x + 5);
        acc = dopos(h0, h1, h2, w1r, w2r, sc1, sh1, sc2, sh2, __high2float(fcB), acc);
        loadcol(h0, hsI[p], x + 6);
        acc = dopos(h1, h2, h0, w1r, w2r, sc1, sh1, sc2, sh2, __low2float(fcC), acc);
        loadcol(h1, hsI[p], x + 7);
        acc = dopos(h2, h0, h1, w1r, w2r, sc1, sh1, sc2, sh2, __high2float(fcC), acc);
      }
    }
    float ax = acc.x, ay = acc.y;
#pragma unroll
    for (int off = 32; off > 0; off >>= 1) {
      ax += __shfl_down(ax, off, 64);
      ay += __shfl_down(ay, off, 64);
    }
    if ((tid & 63) == 0) { red[p][tid >> 6][0] = ax; red[p][tid >> 6][1] = ay; }
  }
  __syncthreads();
  if (tid < SPB) {
    int p = tid >> 1, comp = tid & 1;
    out[base + tid] = red[p][0][comp] + red[p][1][comp] + red[p][2][comp] +
                      red[p][3][comp] + fcb[0];
  }
}

extern "C" void kernel_launch(void* const* d_in, const int* in_sizes, int n_in,
                              void* d_out, int out_size, void* d_ws, size_t ws_size,
                              hipStream_t stream) {
  const int* xb    = (const int*)d_in[0];
  const float* er  = (const float*)d_in[3];
  const float* ev  = (const float*)d_in[4];
  const float* w1  = (const float*)d_in[5];
  const float* g1  = (const float*)d_in[7];
  const float* be1 = (const float*)d_in[8];
  const float* w2  = (const float*)d_in[9];
  const float* g2  = (const float*)d_in[11];
  const float* be2 = (const float*)d_in[12];
  const float* fcw = (const float*)d_in[13];
  const float* fcb = (const float*)d_in[14];
  float* ws  = (float*)d_ws;
  float* out = (float*)d_out;

  hipMemsetAsync(ws, 0, NSTAT * sizeof(float), stream);
  hipLaunchKernelGGL(stats_kernel, dim3(STATS_BLOCKS), dim3(256), 0, stream,
                     xb, er, ev, ws);
  hipLaunchKernelGGL(finalize_kernel, dim3(1), dim3(256), 0, stream,
                     w1, w2, g1, be1, g2, be2, ws);
  hipLaunchKernelGGL(main_kernel, dim3(MAIN_BLOCKS), dim3(256), 0, stream,
                     xb, er, ev, w1, w2, fcw, fcb, ws, out);
}

// Round 5
// 91.457 us; speedup vs baseline: 3.2417x; 1.0675x over previous
//
#include <hip/hip_runtime.h>
#include <hip/hip_fp16.h>

#define BB 2048
#define EMB 128
#define NF 200
#define W_OUT 126
#define EPS 1e-5f

#define SPB 4                     // samples per block (2 pairs)
#define MAIN_BLOCKS (BB / SPB)    // 512

#define SLOTS 6
#define NTASK 42
#define NPAIR 33
#define NGRAM 297
#define NSTAT 324
#define STATS_BLOCKS 342

#define PKD_OFF 3456              // float offset of packed per-f params in ws
#define PKD_STRIDE 32

typedef float f32x2 __attribute__((ext_vector_type(2)));

__device__ __forceinline__ f32x2 fma2(f32x2 a, float s, f32x2 c) {
  return __builtin_elementwise_fma(a, (f32x2){s, s}, c);
}
__device__ __forceinline__ f32x2 fmss(f32x2 a, float s, float sh) {
  return __builtin_elementwise_fma(a, (f32x2){s, s}, (f32x2){sh, sh});
}
__device__ __forceinline__ f32x2 min2(f32x2 a, f32x2 b) {
  return __builtin_elementwise_min(a, b);
}

// ---------------- stats (Gram): unchanged from R3/R4 (proven) --------------
__device__ __constant__ unsigned char PA_t[NTASK] = {
  0,0,0,1,1,2,
  0,1,2,0,1,2, 3,3,4,
  0,1,2,0,1,2, 5,5,6,
  0,1,2,0,1,2, 7,7,8,
  0,1,2,3,4,5,6,7,8};
__device__ __constant__ unsigned char PB_t[NTASK] = {
  0,1,2,1,2,2,
  3,3,3,4,4,4, 3,4,4,
  5,5,5,6,6,6, 5,6,6,
  7,7,7,8,8,8, 7,8,8,
  9,9,9,9,9,9,9,9,9};

__global__ __launch_bounds__(256, 4) void stats_kernel(
    const int* __restrict__ xb, const float* __restrict__ er,
    const float* __restrict__ ev, float* __restrict__ ws) {
  __shared__ float hs[SLOTS][10][132];
  __shared__ const float* volatile rowp[SLOTS][9];
  __shared__ float red[NSTAT];
  const int tid = threadIdx.x;
  for (int e = tid; e < SLOTS * EMB; e += 256) hs[e / EMB][9][e & 127] = 1.0f;
  for (int e = tid; e < NSTAT; e += 256) red[e] = 0.f;

  const int base = blockIdx.x * SLOTS;
  if (tid < SLOTS * 9) {
    int s = tid / 9, r = tid % 9;
    int b = base + s;
    const float* p = nullptr;
    if (b < BB) {
      const int* xr = xb + b * 10;
      if (r == 0)      p = ev + (size_t)xr[1] * EMB;
      else if (r == 1) p = er + (size_t)xr[0] * EMB;
      else if (r == 2) p = ev + (size_t)xr[3] * EMB;
      else {
        int k = (r - 3) >> 1;
        p = ((r - 3) & 1) ? ev + (size_t)xr[5 + 2 * k] * EMB
                          : er + (size_t)xr[4 + 2 * k] * EMB;
      }
    }
    rowp[s][r] = p;
  }
  __syncthreads();
  for (int e = tid; e < SLOTS * 9 * EMB; e += 256) {
    int s = e / (9 * EMB), rem = e % (9 * EMB);
    int r = rem >> 7, col = rem & 127;
    const float* p = (const float*)rowp[s][r];
    hs[s][r][col] = p ? p[col] : 0.f;
  }
  __syncthreads();

  const int slot = tid / NTASK;
  const int task = tid % NTASK;
  if (tid < SLOTS * NTASK) {
    const float* A  = &hs[slot][PA_t[task]][0];
    const float* Bq = &hs[slot][PB_t[task]][0];
    float a00 = 0.f, a01 = 0.f, a02 = 0.f;
    float a10 = 0.f, a11 = 0.f, a12 = 0.f;
    float a20 = 0.f, a21 = 0.f, a22 = 0.f;
    float wa0 = A[0], wa1 = A[1], wb0 = Bq[0], wb1 = Bq[1];
#pragma unroll 3
    for (int x = 0; x < W_OUT; ++x) {
      float wa2 = A[x + 2], wb2 = Bq[x + 2];
      a00 = fmaf(wa0, wb0, a00); a01 = fmaf(wa0, wb1, a01); a02 = fmaf(wa0, wb2, a02);
      a10 = fmaf(wa1, wb0, a10); a11 = fmaf(wa1, wb1, a11); a12 = fmaf(wa1, wb2, a12);
      a20 = fmaf(wa2, wb0, a20); a21 = fmaf(wa2, wb1, a21); a22 = fmaf(wa2, wb2, a22);
      wa0 = wa1; wa1 = wa2; wb0 = wb1; wb1 = wb2;
    }
    if (task < NPAIR) {
      const int o = task * 9;
      atomicAdd(&red[o + 0], a00); atomicAdd(&red[o + 1], a01); atomicAdd(&red[o + 2], a02);
      atomicAdd(&red[o + 3], a10); atomicAdd(&red[o + 4], a11); atomicAdd(&red[o + 5], a12);
      atomicAdd(&red[o + 6], a20); atomicAdd(&red[o + 7], a21); atomicAdd(&red[o + 8], a22);
    } else {
      const int o = NGRAM + (task - NPAIR) * 3;
      atomicAdd(&red[o + 0], a00); atomicAdd(&red[o + 1], a10); atomicAdd(&red[o + 2], a20);
    }
  }
  __syncthreads();
  for (int e = tid; e < NSTAT; e += 256) atomicAdd(&ws[e], red[e]);
}

__device__ __forceinline__ float qform(const float* G, int p,
                                       const float* wa, const float* wb) {
  float t = 0.f;
#pragma unroll
  for (int j = 0; j < 3; j++)
#pragma unroll
    for (int jp = 0; jp < 3; jp++)
      t = fmaf(wa[j] * wb[jp], G[p * 9 + j * 3 + jp], t);
  return t;
}

__global__ __launch_bounds__(256) void finalize_kernel(
    const float* __restrict__ w1, const float* __restrict__ w2,
    const float* __restrict__ g1, const float* __restrict__ be1,
    const float* __restrict__ g2, const float* __restrict__ be2,
    float* __restrict__ ws, int have_pkd) {
  __shared__ float G[NSTAT];
  const int tid = threadIdx.x;
  for (int e = tid; e < NSTAT; e += 256) G[e] = ws[e];
  __syncthreads();
  const int f = tid;
  if (f >= NF) return;
  float w1r[9], w2r[15];
#pragma unroll
  for (int j = 0; j < 9; j++)  w1r[j] = w1[f * 9 + j];
#pragma unroll
  for (int j = 0; j < 15; j++) w2r[j] = w2[f * 15 + j];
  const float invN = 1.0f / (float)(BB * W_OUT);
  const float* Sm = &G[NGRAM];

  float m1 = 0.f;
#pragma unroll
  for (int r = 0; r < 3; r++)
#pragma unroll
    for (int j = 0; j < 3; j++) m1 = fmaf(w1r[r * 3 + j], Sm[r * 3 + j], m1);
  float q1 = qform(G, 0, w1r, w1r) + 2.f * qform(G, 1, w1r, w1r + 3)
           + 2.f * qform(G, 2, w1r, w1r + 6) + qform(G, 3, w1r + 3, w1r + 3)
           + 2.f * qform(G, 4, w1r + 3, w1r + 6) + qform(G, 5, w1r + 6, w1r + 6);
  m1 *= invN;
  float v1 = q1 * invN - m1 * m1;
  float sc1 = g1[f] * rsqrtf(v1 + EPS);
  ws[1600 + f] = sc1;
  ws[1800 + f] = be1[f] - m1 * sc1;

  float mc = 0.f;
#pragma unroll
  for (int r = 0; r < 3; r++)
#pragma unroll
    for (int j = 0; j < 3; j++) mc = fmaf(w2r[r * 3 + j], Sm[r * 3 + j], mc);
  float qc = qform(G, 0, w2r, w2r) + 2.f * qform(G, 1, w2r, w2r + 3)
           + 2.f * qform(G, 2, w2r, w2r + 6) + qform(G, 3, w2r + 3, w2r + 3)
           + 2.f * qform(G, 4, w2r + 3, w2r + 6) + qform(G, 5, w2r + 6, w2r + 6);
  const float* wA = w2r + 9;
  const float* wB = w2r + 12;
  float sc2o[3], sh2o[3];
#pragma unroll
  for (int k = 0; k < 3; k++) {
    const int a = 3 + 2 * k, b = 4 + 2 * k, p0 = 6 + 9 * k;
    float m2 = mc;
#pragma unroll
    for (int j = 0; j < 3; j++) {
      m2 = fmaf(wA[j], Sm[a * 3 + j], m2);
      m2 = fmaf(wB[j], Sm[b * 3 + j], m2);
    }
    float q2 = qc
      + 2.f * (qform(G, p0 + 0, w2r, wA) + qform(G, p0 + 1, w2r + 3, wA)
             + qform(G, p0 + 2, w2r + 6, wA) + qform(G, p0 + 3, w2r, wB)
             + qform(G, p0 + 4, w2r + 3, wB) + qform(G, p0 + 5, w2r + 6, wB))
      + qform(G, p0 + 6, wA, wA) + 2.f * qform(G, p0 + 7, wA, wB)
      + qform(G, p0 + 8, wB, wB);
    m2 *= invN;
    float v2 = q2 * invN - m2 * m2;
    float sck = g2[f] * rsqrtf(v2 + EPS);
    sc2o[k] = sck;
    sh2o[k] = be2[f] - m2 * sck;
    ws[2000 + k * 200 + f] = sck;
    ws[2600 + k * 200 + f] = sh2o[k];
  }

  if (have_pkd) {
    float* pp = ws + PKD_OFF + f * PKD_STRIDE;
#pragma unroll
    for (int j = 0; j < 9; j++)  pp[j] = w1r[j];
#pragma unroll
    for (int j = 0; j < 15; j++) pp[9 + j] = w2r[j];
    pp[24] = ws[1600 + f];
    pp[25] = ws[1800 + f];
#pragma unroll
    for (int k = 0; k < 3; k++) { pp[26 + k] = sc2o[k]; pp[29 + k] = sh2o[k]; }
  }
}

// ---------------- main (new): thread = x position, loop over f --------------
__global__ __launch_bounds__(256, 3) void main_x_kernel(
    const int* __restrict__ xb, const float* __restrict__ er,
    const float* __restrict__ ev, const float* __restrict__ fcw,
    const float* __restrict__ fcb, const float* __restrict__ ws,
    float* __restrict__ out) {
  __shared__ f32x2 hsI[2][9][132];     // paired samples, cols 128..131 zeroed
  __shared__ const float* volatile rowp[SPB][9];
  __shared__ f32x2 red[4];
  const int tid = threadIdx.x;
  const int p = tid >> 7;              // pair index (0,1)
  const int x = tid & 127;             // output position (0..125 active)
  const int base = blockIdx.x * SPB;

  if (tid < SPB * 9) {
    int s = tid / 9, r = tid % 9;
    const int* xr = xb + (size_t)(base + s) * 10;
    const float* q;
    if (r == 0)      q = ev + (size_t)xr[1] * EMB;
    else if (r == 1) q = er + (size_t)xr[0] * EMB;
    else if (r == 2) q = ev + (size_t)xr[3] * EMB;
    else {
      int k = (r - 3) >> 1;
      q = ((r - 3) & 1) ? ev + (size_t)xr[5 + 2 * k] * EMB
                        : er + (size_t)xr[4 + 2 * k] * EMB;
    }
    rowp[s][r] = q;
  }
  __syncthreads();
  for (int e = tid; e < 2 * 9 * 132; e += 256) {
    int pp_ = e / (9 * 132), rem = e % (9 * 132);
    int r = rem / 132, col = rem % 132;
    const float* ra = rowp[2 * pp_][r];
    const float* rb = rowp[2 * pp_ + 1][r];
    hsI[pp_][r][col] = (col < EMB) ? (f32x2){ra[col], rb[col]} : (f32x2){0.f, 0.f};
  }
  __syncthreads();

  // pull this thread's 9x3 window into registers (one-time LDS cost)
  f32x2 A[9], Bq[9], C[9];
#pragma unroll
  for (int r = 0; r < 9; r++) {
    A[r]  = hsI[p][r][x];
    Bq[r] = hsI[p][r][x + 1];
    C[r]  = hsI[p][r][x + 2];
  }

  const float* __restrict__ pkd = ws + PKD_OFF;
  const bool valid = (x < W_OUT);
  f32x2 acc = {0.f, 0.f};

#pragma unroll 2
  for (int f = 0; f < NF; ++f) {
    const float* __restrict__ pp = pkd + f * PKD_STRIDE;  // uniform -> s_load
    float wp[32];
#pragma unroll
    for (int j = 0; j < 32; j++) wp[j] = pp[j];
    float fcv = valid ? fcw[f * W_OUT + x] : 0.f;         // coalesced

    f32x2 r1 = A[0] * wp[0];
    r1 = fma2(Bq[0], wp[1], r1); r1 = fma2(C[0], wp[2], r1);
    r1 = fma2(A[1], wp[3], r1);  r1 = fma2(Bq[1], wp[4], r1);
    r1 = fma2(C[1], wp[5], r1);  r1 = fma2(A[2], wp[6], r1);
    r1 = fma2(Bq[2], wp[7], r1); r1 = fma2(C[2], wp[8], r1);

    f32x2 cm = A[0] * wp[9];
    cm = fma2(Bq[0], wp[10], cm); cm = fma2(C[0], wp[11], cm);
    cm = fma2(A[1], wp[12], cm);  cm = fma2(Bq[1], wp[13], cm);
    cm = fma2(C[1], wp[14], cm);  cm = fma2(A[2], wp[15], cm);
    cm = fma2(Bq[2], wp[16], cm); cm = fma2(C[2], wp[17], cm);

    f32x2 rk0 = fma2(A[3], wp[18], cm);
    rk0 = fma2(Bq[3], wp[19], rk0); rk0 = fma2(C[3], wp[20], rk0);
    rk0 = fma2(A[4], wp[21], rk0);  rk0 = fma2(Bq[4], wp[22], rk0);
    rk0 = fma2(C[4], wp[23], rk0);

    f32x2 rk1 = fma2(A[5], wp[18], cm);
    rk1 = fma2(Bq[5], wp[19], rk1); rk1 = fma2(C[5], wp[20], rk1);
    rk1 = fma2(A[6], wp[21], rk1);  rk1 = fma2(Bq[6], wp[22], rk1);
    rk1 = fma2(C[6], wp[23], rk1);

    f32x2 rk2 = fma2(A[7], wp[18], cm);
    rk2 = fma2(Bq[7], wp[19], rk2); rk2 = fma2(C[7], wp[20], rk2);
    rk2 = fma2(A[8], wp[21], rk2);  rk2 = fma2(Bq[8], wp[22], rk2);
    rk2 = fma2(C[8], wp[23], rk2);

    f32x2 mv = fmss(r1, wp[24], wp[25]);
    mv = min2(mv, fmss(rk0, wp[26], wp[29]));
    mv = min2(mv, fmss(rk1, wp[27], wp[30]));
    mv = min2(mv, fmss(rk2, wp[28], wp[31]));
    mv = __builtin_elementwise_max(mv, (f32x2){0.f, 0.f});
    acc = fma2(mv, fcv, acc);
  }

  float ax = acc.x, ay = acc.y;
#pragma unroll
  for (int off = 32; off > 0; off >>= 1) {
    ax += __shfl_down(ax, off, 64);
    ay += __shfl_down(ay, off, 64);
  }
  if ((tid & 63) == 0) red[tid >> 6] = (f32x2){ax, ay};
  __syncthreads();
  if (tid < 4) {
    int pr = tid >> 1, c = tid & 1;
    f32x2 r0 = red[2 * pr], r1v = red[2 * pr + 1];
    float v = (c ? (r0.y + r1v.y) : (r0.x + r1v.x)) + fcb[0];
    out[base + 2 * pr + c] = v;
  }
}

// ---------------- main (fallback): R4 LDS version ---------------------------
__device__ __forceinline__ void loadcol(f32x2 (&d)[9],
                                        const f32x2 (&hp)[9][EMB], int col) {
#pragma unroll
  for (int r = 0; r < 9; r++) d[r] = hp[r][col];
}

__device__ __forceinline__ f32x2 dopos(
    const f32x2 (&A)[9], const f32x2 (&B)[9], const f32x2 (&C)[9],
    const float (&w1r)[9], const float (&w2r)[15],
    float sc1, float sh1, const float (&sc2)[3], const float (&sh2)[3],
    float fpv, f32x2 acc) {
  f32x2 r1 = A[0] * w1r[0];
  r1 = fma2(B[0], w1r[1], r1); r1 = fma2(C[0], w1r[2], r1);
  r1 = fma2(A[1], w1r[3], r1); r1 = fma2(B[1], w1r[4], r1);
  r1 = fma2(C[1], w1r[5], r1); r1 = fma2(A[2], w1r[6], r1);
  r1 = fma2(B[2], w1r[7], r1); r1 = fma2(C[2], w1r[8], r1);
  f32x2 cm = A[0] * w2r[0];
  cm = fma2(B[0], w2r[1], cm); cm = fma2(C[0], w2r[2], cm);
  cm = fma2(A[1], w2r[3], cm); cm = fma2(B[1], w2r[4], cm);
  cm = fma2(C[1], w2r[5], cm); cm = fma2(A[2], w2r[6], cm);
  cm = fma2(B[2], w2r[7], cm); cm = fma2(C[2], w2r[8], cm);
  f32x2 rk0 = fma2(A[3], w2r[9], cm);
  rk0 = fma2(B[3], w2r[10], rk0); rk0 = fma2(C[3], w2r[11], rk0);
  rk0 = fma2(A[4], w2r[12], rk0); rk0 = fma2(B[4], w2r[13], rk0);
  rk0 = fma2(C[4], w2r[14], rk0);
  f32x2 rk1 = fma2(A[5], w2r[9], cm);
  rk1 = fma2(B[5], w2r[10], rk1); rk1 = fma2(C[5], w2r[11], rk1);
  rk1 = fma2(A[6], w2r[12], rk1); rk1 = fma2(B[6], w2r[13], rk1);
  rk1 = fma2(C[6], w2r[14], rk1);
  f32x2 rk2 = fma2(A[7], w2r[9], cm);
  rk2 = fma2(B[7], w2r[10], rk2); rk2 = fma2(C[7], w2r[11], rk2);
  rk2 = fma2(A[8], w2r[12], rk2); rk2 = fma2(B[8], w2r[13], rk2);
  rk2 = fma2(C[8], w2r[14], rk2);
  f32x2 mv = fmss(r1, sc1, sh1);
  mv = min2(mv, fmss(rk0, sc2[0], sh2[0]));
  mv = min2(mv, fmss(rk1, sc2[1], sh2[1]));
  mv = min2(mv, fmss(rk2, sc2[2], sh2[2]));
  mv = __builtin_elementwise_max(mv, (f32x2){0.f, 0.f});
  return fma2(mv, fpv, acc);
}

__global__ __launch_bounds__(256, 2) void main_lds_kernel(
    const int* __restrict__ xb, const float* __restrict__ er,
    const float* __restrict__ ev, const float* __restrict__ w1,
    const float* __restrict__ w2, const float* __restrict__ fcw,
    const float* __restrict__ fcb, const float* __restrict__ ws,
    float* __restrict__ out) {
  __shared__ f32x2 hsI[2][9][EMB];
  __shared__ __half2 fcwP[63][201];
  __shared__ const float* rowp[SPB][9];
  __shared__ float red[2][4][2];
  const int tid = threadIdx.x;
  const int f = tid;
  const int base = blockIdx.x * SPB;

  float* wsc = (float*)&fcwP[0][0];
  for (int i = tid; i < NF * 9; i += 256)  wsc[i] = w1[i];
  for (int i = tid; i < NF * 15; i += 256) wsc[NF * 9 + i] = w2[i];
  if (tid < SPB * 9) {
    int s = tid / 9, r = tid % 9;
    const int* xr = xb + (size_t)(base + s) * 10;
    const float* q;
    if (r == 0)      q = ev + (size_t)xr[1] * EMB;
    else if (r == 1) q = er + (size_t)xr[0] * EMB;
    else if (r == 2) q = ev + (size_t)xr[3] * EMB;
    else {
      int k = (r - 3) >> 1;
      q = ((r - 3) & 1) ? ev + (size_t)xr[5 + 2 * k] * EMB
                        : er + (size_t)xr[4 + 2 * k] * EMB;
    }
    rowp[s][r] = q;
  }
  __syncthreads();

  float w1r[9], w2r[15];
  float sc1 = 0.f, sh1 = 0.f, sc2[3] = {0.f, 0.f, 0.f}, sh2[3] = {0.f, 0.f, 0.f};
  if (f < NF) {
#pragma unroll
    for (int j = 0; j < 9; j++)  w1r[j] = wsc[f * 9 + j];
#pragma unroll
    for (int j = 0; j < 15; j++) w2r[j] = wsc[NF * 9 + f * 15 + j];
    sc1 = ws[1600 + f]; sh1 = ws[1800 + f];
#pragma unroll
    for (int k = 0; k < 3; k++) {
      sc2[k] = ws[2000 + k * 200 + f];
      sh2[k] = ws[2600 + k * 200 + f];
    }
  }
  __syncthreads();

  for (int i = tid; i < 63 * NF; i += 256) {
    int ff = i / 63, c = i % 63;
    const float2 v = *(const float2*)(fcw + 2 * (size_t)i);
    fcwP[c][ff] = __floats2half2_rn(v.x, v.y);
  }
  for (int e = tid; e < 2 * 9 * EMB; e += 256) {
    int pq = e / (9 * EMB), rem = e % (9 * EMB);
    int r = rem >> 7, x = rem & 127;
    const float* ra = rowp[2 * pq][r];
    const float* rb = rowp[2 * pq + 1][r];
    hsI[pq][r][x] = (f32x2){ra[x], rb[x]};
  }
  __syncthreads();

#pragma unroll 1
  for (int pq = 0; pq < 2; pq++) {
    f32x2 acc = {0.f, 0.f};
    if (f < NF) {
      f32x2 h0[9], h1[9], h2[9];
      loadcol(h0, hsI[pq], 0);
      loadcol(h1, hsI[pq], 1);
#pragma unroll 1
      for (int it = 0; it < 21; it++) {
        const int x = it * 6;
        const __half2 fcA = fcwP[3 * it + 0][f];
        const __half2 fcB = fcwP[3 * it + 1][f];
        const __half2 fcC = fcwP[3 * it + 2][f];
        loadcol(h2, hsI[pq], x + 2);
        acc = dopos(h0, h1, h2, w1r, w2r, sc1, sh1, sc2, sh2, __low2float(fcA), acc);
        loadcol(h0, hsI[pq], x + 3);
        acc = dopos(h1, h2, h0, w1r, w2r, sc1, sh1, sc2, sh2, __high2float(fcA), acc);
        loadcol(h1, hsI[pq], x + 4);
        acc = dopos(h2, h0, h1, w1r, w2r, sc1, sh1, sc2, sh2, __low2float(fcB), acc);
        loadcol(h2, hsI[pq], x + 5);
        acc = dopos(h0, h1, h2, w1r, w2r, sc1, sh1, sc2, sh2, __high2float(fcB), acc);
        loadcol(h0, hsI[pq], x + 6);
        acc = dopos(h1, h2, h0, w1r, w2r, sc1, sh1, sc2, sh2, __low2float(fcC), acc);
        loadcol(h1, hsI[pq], x + 7);
        acc = dopos(h2, h0, h1, w1r, w2r, sc1, sh1, sc2, sh2, __high2float(fcC), acc);
      }
    }
    float ax = acc.x, ay = acc.y;
#pragma unroll
    for (int off = 32; off > 0; off >>= 1) {
      ax += __shfl_down(ax, off, 64);
      ay += __shfl_down(ay, off, 64);
    }
    if ((tid & 63) == 0) { red[pq][tid >> 6][0] = ax; red[pq][tid >> 6][1] = ay; }
  }
  __syncthreads();
  if (tid < SPB) {
    int pq = tid >> 1, comp = tid & 1;
    out[base + tid] = red[pq][0][comp] + red[pq][1][comp] + red[pq][2][comp] +
                      red[pq][3][comp] + fcb[0];
  }
}

extern "C" void kernel_launch(void* const* d_in, const int* in_sizes, int n_in,
                              void* d_out, int out_size, void* d_ws, size_t ws_size,
                              hipStream_t stream) {
  const int* xb    = (const int*)d_in[0];
  const float* er  = (const float*)d_in[3];
  const float* ev  = (const float*)d_in[4];
  const float* w1  = (const float*)d_in[5];
  const float* g1  = (const float*)d_in[7];
  const float* be1 = (const float*)d_in[8];
  const float* w2  = (const float*)d_in[9];
  const float* g2  = (const float*)d_in[11];
  const float* be2 = (const float*)d_in[12];
  const float* fcw = (const float*)d_in[13];
  const float* fcb = (const float*)d_in[14];
  float* ws  = (float*)d_ws;
  float* out = (float*)d_out;

  const size_t need_pkd = (size_t)(PKD_OFF + NF * PKD_STRIDE) * sizeof(float);
  const int use_pkd = (ws_size >= need_pkd) ? 1 : 0;

  hipMemsetAsync(ws, 0, NSTAT * sizeof(float), stream);
  hipLaunchKernelGGL(stats_kernel, dim3(STATS_BLOCKS), dim3(256), 0, stream,
                     xb, er, ev, ws);
  hipLaunchKernelGGL(finalize_kernel, dim3(1), dim3(256), 0, stream,
                     w1, w2, g1, be1, g2, be2, ws, use_pkd);
  if (use_pkd)
    hipLaunchKernelGGL(main_x_kernel, dim3(MAIN_BLOCKS), dim3(256), 0, stream,
                       xb, er, ev, fcw, fcb, ws, out);
  else
    hipLaunchKernelGGL(main_lds_kernel, dim3(MAIN_BLOCKS), dim3(256), 0, stream,
                       xb, er, ev, w1, w2, fcw, fcb, ws, out);
}